// Round 11
// baseline (657.041 us; speedup 1.0000x reference)
//
#include <hip/hip_runtime.h>

#define HH 512
#define WW 512
#define NC 25              // final channel count: 1 + 12*2
#define HWs (HH * WW)

__device__ __forceinline__ int refl(int p, int n) {
    p = (p < 0) ? -p : p;
    p = (p >= n) ? (2 * n - 2 - p) : p;
    return p;
}

__global__ __launch_bounds__(256) void copy_x_kernel(const float* __restrict__ x,
                                                     float* __restrict__ out) {
    int t = blockIdx.x * 256 + threadIdx.x;   // NB*HWs/4 = 262144 threads
    int b = t >> 16;                          // HWs/4 = 65536 float4 per batch
    int r = t & 65535;
    const float4* src = (const float4*)(x + (size_t)b * HWs);
    float4* dst = (float4*)(out + (size_t)b * NC * HWs);
    dst[r] = src[r];
}

// ======================= odd-DIL layers: R8 kernel, UNCHANGED ==============
// (best measured: 331.9us total) 6-row dilation-symmetry scheme, 24 dword
// loads / 6 px / channel, XCD swizzle, channel rotation, ping-pong, (256,3).
template <int NIN, int DIL>
__global__ __launch_bounds__(256, 3) void msd_layer_s(const float* __restrict__ wts,
                                                      const float* __restrict__ bias,
                                                      float* __restrict__ buf,
                                                      int layer) {
    constexpr int M6 = 512 / (6 * DIL);
    constexpr int DM = DIL * M6;
    constexpr int SPAN = 6 * DM;
    constexpr int RT = 512 - SPAN;
    constexpr int TCH = (RT + 3) / 4;
    constexpr int IMT = 512 * DM;
    constexpr int NMAIN = 4 * IMT;

    int bid = blockIdx.x;
    {
        const int nblk = gridDim.x;
        const int q = nblk >> 3, r = nblk & 7;
        const int xcd = bid & 7, idx = bid >> 3;
        bid = (xcd < r ? xcd * (q + 1) : r * (q + 1) + (xcd - r) * q) + idx;
    }
    const int t = bid * 256 + threadIdx.x;

    const float b0 = bias[2 * layer];
    const float b1 = bias[2 * layer + 1];

    if (t < NMAIN) {
        const int img = t / IMT;
        const int u = t - img * IMT;
        const int bi = __builtin_amdgcn_readfirstlane(u >> 9);
        const int w = u & 511;
        const int k = bi / DIL, j = bi - k * DIL;
        const int h = 6 * DIL * k + j;

        int rowoff[8];
#pragma unroll
        for (int r = 0; r < 8; ++r) rowoff[r] = refl(h + (r - 1) * DIL, HH) * WW;
        int cw[3];
#pragma unroll
        for (int q = 0; q < 3; ++q) cw[q] = refl(w + (q - 1) * DIL, WW);

        float a0[6], a1[6];
#pragma unroll
        for (int al = 0; al < 6; ++al) { a0[al] = b0; a1[al] = b1; }
        const float* base = buf + (size_t)img * NC * HWs;

        const int c0 = bid - (bid / NIN) * NIN;

        float vA[8][3], vB[8][3];

        auto LD = [&](float (&v)[8][3], int c) {
            const float* plane = base + (size_t)c * HWs;
#pragma unroll
            for (int r = 0; r < 8; ++r) {
                const float* rowp = plane + rowoff[r];
#pragma unroll
                for (int q = 0; q < 3; ++q) v[r][q] = rowp[cw[q]];
            }
        };
        auto FM = [&](const float (&v)[8][3], int c) {
            float wk0[9], wk1[9];
#pragma unroll
            for (int kk = 0; kk < 9; ++kk) {
                wk0[kk] = wts[c * 9 + kk];
                wk1[kk] = wts[(NIN + c) * 9 + kk];
            }
#pragma unroll
            for (int al = 0; al < 6; ++al)
#pragma unroll
                for (int kr = 0; kr < 3; ++kr)
#pragma unroll
                    for (int kw = 0; kw < 3; ++kw) {
                        float vv = v[al + kr][kw];
                        a0[al] = fmaf(vv, wk0[kr * 3 + kw], a0[al]);
                        a1[al] = fmaf(vv, wk1[kr * 3 + kw], a1[al]);
                    }
        };

        LD(vA, c0);
#pragma unroll
        for (int i = 0; i < NIN; i += 2) {
            int cA = c0 + i;     cA -= (cA >= NIN) ? NIN : 0;
            int cB = c0 + i + 1; cB -= (cB >= NIN) ? NIN : 0;
            if (i + 1 < NIN) LD(vB, cB);
            FM(vA, cA);
            if (i + 1 >= NIN) break;
            int cN = c0 + i + 2; cN -= (cN >= NIN) ? NIN : 0;
            if (i + 2 < NIN) LD(vA, cN);
            FM(vB, cB);
        }

        float* o0 = buf + (size_t)(img * NC + NIN) * HWs;
        float* o1 = o0 + HWs;
#pragma unroll
        for (int al = 0; al < 6; ++al) {
            size_t off = (size_t)(h + al * DIL) * WW + (size_t)w;
            o0[off] = fmaxf(a0[al], 0.f);
            o1[off] = fmaxf(a1[al], 0.f);
        }
    } else if (RT > 0) {
        const int t2 = t - NMAIN;
        constexpr int PIT = 512 * TCH;
        const int img = t2 / PIT;
        const int u = t2 - img * PIT;
        const int s = __builtin_amdgcn_readfirstlane(u >> 9);
        const int w = u & 511;
        const int r0 = SPAN + 4 * s;

        int cw[3];
#pragma unroll
        for (int q = 0; q < 3; ++q) cw[q] = refl(w + (q - 1) * DIL, WW);
        int ro[3][4];
#pragma unroll
        for (int kr = 0; kr < 3; ++kr)
#pragma unroll
            for (int i = 0; i < 4; ++i)
                ro[kr][i] = refl(r0 + i + (kr - 1) * DIL, HH) * WW;

        float a0[4] = {b0, b0, b0, b0};
        float a1[4] = {b1, b1, b1, b1};
        const float* base = buf + (size_t)img * NC * HWs;

        for (int c = 0; c < NIN; ++c) {
            const float* plane = base + (size_t)c * HWs;
            float wk0[9], wk1[9];
#pragma unroll
            for (int kk = 0; kk < 9; ++kk) {
                wk0[kk] = wts[c * 9 + kk];
                wk1[kk] = wts[(NIN + c) * 9 + kk];
            }
#pragma unroll
            for (int i = 0; i < 4; ++i) {
                if (r0 + i < HH) {
#pragma unroll
                    for (int kr = 0; kr < 3; ++kr) {
                        const float* rowp = plane + ro[kr][i];
#pragma unroll
                        for (int kw = 0; kw < 3; ++kw) {
                            float vv = rowp[cw[kw]];
                            a0[i] = fmaf(vv, wk0[kr * 3 + kw], a0[i]);
                            a1[i] = fmaf(vv, wk1[kr * 3 + kw], a1[i]);
                        }
                    }
                }
            }
        }

        float* o0 = buf + (size_t)(img * NC + NIN) * HWs;
        float* o1 = o0 + HWs;
#pragma unroll
        for (int i = 0; i < 4; ++i) {
            if (r0 + i < HH) {
                size_t off = (size_t)(r0 + i) * WW + (size_t)w;
                o0[off] = fmaxf(a0[i], 0.f);
                o1[off] = fmaxf(a1[i], 0.f);
            }
        }
    }
}

// ================= even-DIL layers: pair-column float2 scheme ==============
// R11: TA-request reduction (validated lever: R8 -20% req -> -8.5%; R9 shows
// TA ~2.7x oversubscribed vs VALU). For even DIL a thread owning cols
// {2L,2L+1} has all 3 col-taps pair-aligned: pairs {L-D/2, L, L+D/2} ->
// one float2 load replaces two dwords, zero cross-lane. 4-row scheme:
// 18 x2-loads per 8 px = 2.25 req/px vs 4. float2 stores too. Reflection
// edge (<=6 lanes each side, waves 0/3 only) falls back to scalar loads.
// VGPR ~120 (weights live in SGPR) under the (256,2)=128 cap.
template <int NIN, int DIL>
__global__ __launch_bounds__(256, 2) void msd_layer_p(const float* __restrict__ wts,
                                                      const float* __restrict__ bias,
                                                      float* __restrict__ buf,
                                                      int layer) {
    static_assert(DIL % 2 == 0, "pair kernel needs even dilation");
    constexpr int M4 = 512 / (4 * DIL);
    constexpr int DM = DIL * M4;          // row-bases per image
    constexpr int SPAN = 4 * DM;
    constexpr int RT = 512 - SPAN;
    constexpr int TCH = (RT + 3) / 4;
    constexpr int IMT = 256 * DM;         // pair-threads per image
    constexpr int NMAIN = 4 * IMT;
    constexpr int HD = DIL / 2;

    int bid = blockIdx.x;
    {
        const int nblk = gridDim.x;
        const int q = nblk >> 3, r = nblk & 7;
        const int xcd = bid & 7, idx = bid >> 3;
        bid = (xcd < r ? xcd * (q + 1) : r * (q + 1) + (xcd - r) * q) + idx;
    }
    const int t = bid * 256 + threadIdx.x;

    const float b0 = bias[2 * layer];
    const float b1 = bias[2 * layer + 1];

    if (t < NMAIN) {
        const int img = t / IMT;
        const int u = t - img * IMT;
        const int bi = __builtin_amdgcn_readfirstlane(u >> 8);   // row-base/block
        const int lam = u & 255;                                 // pair col
        const int k = bi / DIL, j = bi - k * DIL;
        const int h = 4 * DIL * k + j;                           // scalar row

        int rowoff[6];
#pragma unroll
        for (int r = 0; r < 6; ++r) rowoff[r] = refl(h + (r - 1) * DIL, HH) * WW;

        const int pl = lam - HD, pc = lam, pr = lam + HD;
        const bool eL = (pl < 0), eR = (pr > 255);
        // reflected scalar cols for edge lanes
        const int clx = refl(2 * lam - DIL, WW),     cly = refl(2 * lam + 1 - DIL, WW);
        const int crx = refl(2 * lam + DIL, WW),     cry = refl(2 * lam + 1 + DIL, WW);

        float a0x[4], a0y[4], a1x[4], a1y[4];
#pragma unroll
        for (int al = 0; al < 4; ++al) {
            a0x[al] = b0; a0y[al] = b0; a1x[al] = b1; a1y[al] = b1;
        }
        const float* base = buf + (size_t)img * NC * HWs;

        const int c0 = bid - (bid / NIN) * NIN;      // bid % NIN (rotation)

        float2 vA[6][3], vB[6][3];

        auto LD = [&](float2 (&v)[6][3], int c) {
            const float* plane = base + (size_t)c * HWs;
#pragma unroll
            for (int r = 0; r < 6; ++r) {
                const float* rowp = plane + rowoff[r];
                const float2* rp2 = (const float2*)rowp;
                v[r][0] = eL ? make_float2(rowp[clx], rowp[cly]) : rp2[pl];
                v[r][1] = rp2[pc];
                v[r][2] = eR ? make_float2(rowp[crx], rowp[cry]) : rp2[pr];
            }
        };
        auto FM = [&](const float2 (&v)[6][3], int c) {
            float wk0[9], wk1[9];
#pragma unroll
            for (int kk = 0; kk < 9; ++kk) {
                wk0[kk] = wts[c * 9 + kk];           // uniform -> s_load
                wk1[kk] = wts[(NIN + c) * 9 + kk];
            }
#pragma unroll
            for (int al = 0; al < 4; ++al)
#pragma unroll
                for (int kr = 0; kr < 3; ++kr)
#pragma unroll
                    for (int kw = 0; kw < 3; ++kw) {
                        float2 vv = v[al + kr][kw];
                        float w0 = wk0[kr * 3 + kw], w1 = wk1[kr * 3 + kw];
                        a0x[al] = fmaf(vv.x, w0, a0x[al]);
                        a0y[al] = fmaf(vv.y, w0, a0y[al]);
                        a1x[al] = fmaf(vv.x, w1, a1x[al]);
                        a1y[al] = fmaf(vv.y, w1, a1y[al]);
                    }
        };

        {
            int cA = c0;
            LD(vA, cA);
        }
#pragma unroll
        for (int i = 0; i < NIN; i += 2) {
            int cA = c0 + i;     cA -= (cA >= NIN) ? NIN : 0;
            int cB = c0 + i + 1; cB -= (cB >= NIN) ? NIN : 0;
            if (i + 1 < NIN) LD(vB, cB);
            FM(vA, cA);
            if (i + 1 >= NIN) break;
            int cN = c0 + i + 2; cN -= (cN >= NIN) ? NIN : 0;
            if (i + 2 < NIN) LD(vA, cN);
            FM(vB, cB);
        }

        float* o0 = buf + (size_t)(img * NC + NIN) * HWs;
        float* o1 = o0 + HWs;
#pragma unroll
        for (int al = 0; al < 4; ++al) {
            float2* p0 = (float2*)(o0 + (size_t)(h + al * DIL) * WW);
            float2* p1 = (float2*)(o1 + (size_t)(h + al * DIL) * WW);
            p0[lam] = make_float2(fmaxf(a0x[al], 0.f), fmaxf(a0y[al], 0.f));
            p1[lam] = make_float2(fmaxf(a1x[al], 0.f), fmaxf(a1y[al], 0.f));
        }
    } else if (RT > 0) {
        const int t2 = t - NMAIN;
        constexpr int PIT = 512 * TCH;
        const int img = t2 / PIT;
        const int u = t2 - img * PIT;
        const int s = __builtin_amdgcn_readfirstlane(u >> 9);
        const int w = u & 511;
        const int r0 = SPAN + 4 * s;

        int cw[3];
#pragma unroll
        for (int q = 0; q < 3; ++q) cw[q] = refl(w + (q - 1) * DIL, WW);
        int ro[3][4];
#pragma unroll
        for (int kr = 0; kr < 3; ++kr)
#pragma unroll
            for (int i = 0; i < 4; ++i)
                ro[kr][i] = refl(r0 + i + (kr - 1) * DIL, HH) * WW;

        float a0[4] = {b0, b0, b0, b0};
        float a1[4] = {b1, b1, b1, b1};
        const float* base = buf + (size_t)img * NC * HWs;

        for (int c = 0; c < NIN; ++c) {
            const float* plane = base + (size_t)c * HWs;
            float wk0[9], wk1[9];
#pragma unroll
            for (int kk = 0; kk < 9; ++kk) {
                wk0[kk] = wts[c * 9 + kk];
                wk1[kk] = wts[(NIN + c) * 9 + kk];
            }
#pragma unroll
            for (int i = 0; i < 4; ++i) {
                if (r0 + i < HH) {
#pragma unroll
                    for (int kr = 0; kr < 3; ++kr) {
                        const float* rowp = plane + ro[kr][i];
#pragma unroll
                        for (int kw = 0; kw < 3; ++kw) {
                            float vv = rowp[cw[kw]];
                            a0[i] = fmaf(vv, wk0[kr * 3 + kw], a0[i]);
                            a1[i] = fmaf(vv, wk1[kr * 3 + kw], a1[i]);
                        }
                    }
                }
            }
        }

        float* o0 = buf + (size_t)(img * NC + NIN) * HWs;
        float* o1 = o0 + HWs;
#pragma unroll
        for (int i = 0; i < 4; ++i) {
            if (r0 + i < HH) {
                size_t off = (size_t)(r0 + i) * WW + (size_t)w;
                o0[off] = fmaxf(a0[i], 0.f);
                o1[off] = fmaxf(a1[i], 0.f);
            }
        }
    }
}

extern "C" void kernel_launch(void* const* d_in, const int* in_sizes, int n_in,
                              void* d_out, int out_size, void* d_ws, size_t ws_size,
                              hipStream_t stream) {
    const float* x = (const float*)d_in[0];
    const float* bias = (const float*)d_in[1];
    float* out = (float*)d_out;

    copy_x_kernel<<<1024, 256, 0, stream>>>(x, out);

// scalar (odd DIL): blocks = 8*DM + 8*TCH  (6-row scheme)
#define GBLKS(dil) (8 * ((dil) * (512 / (6 * (dil)))) \
                  + 8 * (((512 - 6 * ((dil) * (512 / (6 * (dil))))) + 3) / 4))
// pair (even DIL): blocks = 4*DM + 8*TCH  (4-row, 2-col scheme)
#define GBLKP(dil) (4 * ((dil) * (512 / (4 * (dil)))) \
                  + 8 * (((512 - 4 * ((dil) * (512 / (4 * (dil))))) + 3) / 4))
#define LAYERS(i, nin, dil) \
    msd_layer_s<nin, dil><<<GBLKS(dil), 256, 0, stream>>>((const float*)d_in[2 + i], bias, out, i)
#define LAYERP(i, nin, dil) \
    msd_layer_p<nin, dil><<<GBLKP(dil), 256, 0, stream>>>((const float*)d_in[2 + i], bias, out, i)

    LAYERS(0, 1, 1);
    LAYERP(1, 3, 2);
    LAYERS(2, 5, 3);
    LAYERP(3, 7, 4);
    LAYERS(4, 9, 5);
    LAYERP(5, 11, 6);
    LAYERS(6, 13, 7);
    LAYERP(7, 15, 8);
    LAYERS(8, 17, 9);
    LAYERP(9, 19, 10);
    LAYERS(10, 21, 11);
    LAYERP(11, 23, 12);
#undef LAYERS
#undef LAYERP
#undef GBLKS
#undef GBLKP
}

// Round 12
// 338.906 us; speedup vs baseline: 1.9387x; 1.9387x over previous
//
#include <hip/hip_runtime.h>

#define HH 512
#define WW 512
#define NC 25              // final channel count: 1 + 12*2
#define HWs (HH * WW)

// Anti-sinking fence: memory clobber — VMEM loads may not cross it, so the
// compiler cannot sink a prefetch LD block below the following FM block.
// (R11 evidence: without this, regalloc sinks prefetch loads to their uses,
// deleting the software pipeline: VGPR=68 < declared buffers, 3.4x slower.)
#define FENCE() asm volatile("" ::: "memory")

__device__ __forceinline__ int refl(int p, int n) {
    p = (p < 0) ? -p : p;
    p = (p >= n) ? (2 * n - 2 - p) : p;
    return p;
}

__global__ __launch_bounds__(256) void copy_x_kernel(const float* __restrict__ x,
                                                     float* __restrict__ out) {
    int t = blockIdx.x * 256 + threadIdx.x;   // NB*HWs/4 = 262144 threads
    int b = t >> 16;                          // HWs/4 = 65536 float4 per batch
    int r = t & 65535;
    const float4* src = (const float4*)(x + (size_t)b * HWs);
    float4* dst = (float4*)(out + (size_t)b * NC * HWs);
    dst[r] = src[r];
}

// R12: R8's 6-row scheme (best measured, 331.9us) + 2-channel-deep prefetch
// (3 buffers) + FENCE pinning. Coverage = 2 channels x ~260cyc x 2.7
// waves/SIMD ~= 1400 cyc > L2-miss latency (~700-900) -> dependency stall
// (the ~100us gap R9's ablation exposed: pipeline = SUM of load+FMA, not
// MAX) should collapse. (256,2) = 128-VGPR cap; est. live ~105: 3x24 buffer
// + 12 acc + addressing. Grid residency unchanged (grid-capped ~10.8
// waves/CU < 16 allowed). Verification signal: VGPR_Count >= 96 on big
// layers means the pipeline survived regalloc; <= 90 means defeated again.
template <int NIN, int DIL>
__global__ __launch_bounds__(256, 2) void msd_layer(const float* __restrict__ wts,
                                                    const float* __restrict__ bias,
                                                    float* __restrict__ buf,
                                                    int layer) {
    constexpr int M6 = 512 / (6 * DIL);
    constexpr int DM = DIL * M6;          // row-bases per image
    constexpr int SPAN = 6 * DM;          // rows covered by main path
    constexpr int RT = 512 - SPAN;        // tail rows (0..50)
    constexpr int TCH = (RT + 3) / 4;     // tail chunks of 4 rows
    constexpr int IMT = 512 * DM;         // main threads per image
    constexpr int NMAIN = 4 * IMT;

    // ---- bijective chunked XCD swizzle (MI355X: 8 XCDs, round-robin) ----
    int bid = blockIdx.x;
    {
        const int nblk = gridDim.x;
        const int q = nblk >> 3, r = nblk & 7;
        const int xcd = bid & 7, idx = bid >> 3;
        bid = (xcd < r ? xcd * (q + 1) : r * (q + 1) + (xcd - r) * q) + idx;
    }
    const int t = bid * 256 + threadIdx.x;

    const float b0 = bias[2 * layer];
    const float b1 = bias[2 * layer + 1];

    if (t < NMAIN) {
        const int img = t / IMT;                       // uniform per block
        const int u = t - img * IMT;
        const int bi = __builtin_amdgcn_readfirstlane(u >> 9);   // base index
        const int w = u & 511;                         // per-lane column
        const int k = bi / DIL, j = bi - k * DIL;
        const int h = 6 * DIL * k + j;                 // base output row (scalar)

        int rowoff[8];                                 // rows h+(r-1)*d, scalar
#pragma unroll
        for (int r = 0; r < 8; ++r) rowoff[r] = refl(h + (r - 1) * DIL, HH) * WW;
        int cw[3];                                     // per-lane col taps
#pragma unroll
        for (int q = 0; q < 3; ++q) cw[q] = refl(w + (q - 1) * DIL, WW);

        float a0[6], a1[6];
#pragma unroll
        for (int al = 0; al < 6; ++al) { a0[al] = b0; a1[al] = b1; }
        const float* base = buf + (size_t)img * NC * HWs;

        // per-block channel-rotation start (scalar; NIN is compile-time)
        const int c0 = bid - (bid / NIN) * NIN;        // bid % NIN

        float v0[8][3], v1[8][3], v2[8][3];            // 3-deep rotation

        auto LD = [&](float (&v)[8][3], int c) {
            int cc = c0 + c; cc -= (cc >= NIN) ? NIN : 0;
            const float* plane = base + (size_t)cc * HWs;
#pragma unroll
            for (int r = 0; r < 8; ++r) {
                const float* rowp = plane + rowoff[r];
#pragma unroll
                for (int q = 0; q < 3; ++q) v[r][q] = rowp[cw[q]];
            }
        };
        auto FM = [&](const float (&v)[8][3], int c) {
            int cc = c0 + c; cc -= (cc >= NIN) ? NIN : 0;
            float wk0[9], wk1[9];
#pragma unroll
            for (int kk = 0; kk < 9; ++kk) {
                wk0[kk] = wts[cc * 9 + kk];            // uniform -> s_load
                wk1[kk] = wts[(NIN + cc) * 9 + kk];
            }
#pragma unroll
            for (int al = 0; al < 6; ++al)
#pragma unroll
                for (int kr = 0; kr < 3; ++kr)
#pragma unroll
                    for (int kw = 0; kw < 3; ++kw) {
                        float vv = v[al + kr][kw];
                        a0[al] = fmaf(vv, wk0[kr * 3 + kw], a0[al]);
                        a1[al] = fmaf(vv, wk1[kr * 3 + kw], a1[al]);
                    }
        };

        // ---- 2-deep software pipeline, fences forbid load-sinking ----
        LD(v0, 0);
        FENCE();
        if (1 < NIN) { LD(v1, 1); }
        FENCE();
#pragma unroll
        for (int c = 0; c < NIN; ++c) {
            // static buffer selection (c is a compile-time unroll constant)
            float (&cur)[8][3] = (c % 3 == 0) ? v0 : ((c % 3 == 1) ? v1 : v2);
            float (&nxt)[8][3] = ((c + 2) % 3 == 0) ? v0
                               : (((c + 2) % 3 == 1) ? v1 : v2);
            if (c + 2 < NIN) LD(nxt, c + 2);           // 2-channel-deep prefetch
            FENCE();                                    // pin LD above FM
            FM(cur, c);
        }

        float* o0 = buf + (size_t)(img * NC + NIN) * HWs;
        float* o1 = o0 + HWs;
#pragma unroll
        for (int al = 0; al < 6; ++al) {
            size_t off = (size_t)(h + al * DIL) * WW + (size_t)w;
            o0[off] = fmaxf(a0[al], 0.f);
            o1[off] = fmaxf(a1[al], 0.f);
        }
    } else if (RT > 0) {
        const int t2 = t - NMAIN;
        constexpr int PIT = 512 * TCH;
        const int img = t2 / PIT;
        const int u = t2 - img * PIT;
        const int s = __builtin_amdgcn_readfirstlane(u >> 9);
        const int w = u & 511;
        const int r0 = SPAN + 4 * s;

        int cw[3];
#pragma unroll
        for (int q = 0; q < 3; ++q) cw[q] = refl(w + (q - 1) * DIL, WW);
        int ro[3][4];
#pragma unroll
        for (int kr = 0; kr < 3; ++kr)
#pragma unroll
            for (int i = 0; i < 4; ++i)
                ro[kr][i] = refl(r0 + i + (kr - 1) * DIL, HH) * WW;

        float a0[4] = {b0, b0, b0, b0};
        float a1[4] = {b1, b1, b1, b1};
        const float* base = buf + (size_t)img * NC * HWs;

        for (int c = 0; c < NIN; ++c) {
            const float* plane = base + (size_t)c * HWs;
            float wk0[9], wk1[9];
#pragma unroll
            for (int kk = 0; kk < 9; ++kk) {
                wk0[kk] = wts[c * 9 + kk];
                wk1[kk] = wts[(NIN + c) * 9 + kk];
            }
#pragma unroll
            for (int i = 0; i < 4; ++i) {
                if (r0 + i < HH) {
#pragma unroll
                    for (int kr = 0; kr < 3; ++kr) {
                        const float* rowp = plane + ro[kr][i];
#pragma unroll
                        for (int kw = 0; kw < 3; ++kw) {
                            float vv = rowp[cw[kw]];
                            a0[i] = fmaf(vv, wk0[kr * 3 + kw], a0[i]);
                            a1[i] = fmaf(vv, wk1[kr * 3 + kw], a1[i]);
                        }
                    }
                }
            }
        }

        float* o0 = buf + (size_t)(img * NC + NIN) * HWs;
        float* o1 = o0 + HWs;
#pragma unroll
        for (int i = 0; i < 4; ++i) {
            if (r0 + i < HH) {
                size_t off = (size_t)(r0 + i) * WW + (size_t)w;
                o0[off] = fmaxf(a0[i], 0.f);
                o1[off] = fmaxf(a1[i], 0.f);
            }
        }
    }
}

extern "C" void kernel_launch(void* const* d_in, const int* in_sizes, int n_in,
                              void* d_out, int out_size, void* d_ws, size_t ws_size,
                              hipStream_t stream) {
    const float* x = (const float*)d_in[0];
    const float* bias = (const float*)d_in[1];
    float* out = (float*)d_out;

    copy_x_kernel<<<1024, 256, 0, stream>>>(x, out);

// blocks = (main + tail threads)/256 = 8*DM + 8*TCH  (6-row scheme)
#define GBLK(dil) (8 * ((dil) * (512 / (6 * (dil)))) \
                 + 8 * (((512 - 6 * ((dil) * (512 / (6 * (dil))))) + 3) / 4))
#define LAYER(i, nin, dil) \
    msd_layer<nin, dil><<<GBLK(dil), 256, 0, stream>>>((const float*)d_in[2 + i], bias, out, i)

    LAYER(0, 1, 1);
    LAYER(1, 3, 2);
    LAYER(2, 5, 3);
    LAYER(3, 7, 4);
    LAYER(4, 9, 5);
    LAYER(5, 11, 6);
    LAYER(6, 13, 7);
    LAYER(7, 15, 8);
    LAYER(8, 17, 9);
    LAYER(9, 19, 10);
    LAYER(10, 21, 11);
    LAYER(11, 23, 12);
#undef LAYER
#undef GBLK
}